// Round 1
// baseline (370.863 us; speedup 1.0000x reference)
//
#include <hip/hip_runtime.h>

// VQ-VAE quantizer: z [16,4096,64] f32, embedding [1024,64] f32.
// Outputs concatenated in d_out (float32): [0]=loss, [1..4194304]=z_q,
// [4194305..]=argmin indices (as float).
//
// Correctness-critical: argmin must match the numpy fp32 reference.
// d = (zz + ee) - 2*dot, where zz = np pairwise sum of z*z (8-accumulator
// tree, contraction OFF), and fmaf(-2,dot,t1) == round(t1 - 2*dot) since
// 2*dot is exact. Near-ties (~50 rows within 1 ulp of 64) are then resolved
// identically to numpy except with prob ~ O(1e-1) total.

#define D 64
#define ROWS_PER_BLOCK 128
#define TPB 256
#define LDS_STRIDE 68  // 64 + 4 pad to break power-of-2 LDS banking

__global__ __launch_bounds__(TPB) void ee_kernel(const float* __restrict__ emb,
                                                 float* __restrict__ ee, int n_e) {
    int j = blockIdx.x * blockDim.x + threadIdx.x;
    if (j >= n_e) return;
    const float4* e4 = (const float4*)(emb + (size_t)j * D);
    float x[D];
#pragma unroll
    for (int c = 0; c < 16; ++c) {
        float4 v = e4[c];
        x[4*c+0] = v.x; x[4*c+1] = v.y; x[4*c+2] = v.z; x[4*c+3] = v.w;
    }
    {
#pragma clang fp contract(off)
        // numpy pairwise_sum order for n=64: 8 accumulators, sequential over
        // stride-8 columns, then ((r0+r1)+(r2+r3))+((r4+r5)+(r6+r7)).
        float r[8];
#pragma unroll
        for (int jj = 0; jj < 8; ++jj) { float t = x[jj] * x[jj]; r[jj] = t; }
#pragma unroll
        for (int i = 8; i < 64; i += 8) {
#pragma unroll
            for (int jj = 0; jj < 8; ++jj) { float t = x[i+jj] * x[i+jj]; r[jj] = r[jj] + t; }
        }
        ee[j] = ((r[0]+r[1]) + (r[2]+r[3])) + ((r[4]+r[5]) + (r[6]+r[7]));
    }
}

__global__ __launch_bounds__(TPB) void vq_kernel(const float* __restrict__ z,
                                                 const float* __restrict__ emb,
                                                 const float* __restrict__ ee,
                                                 float* __restrict__ out_loss,
                                                 float* __restrict__ out_zq,
                                                 float* __restrict__ out_idx,
                                                 float loss_scale) {
    __shared__ float lds_z[ROWS_PER_BLOCK * LDS_STRIDE];
    __shared__ float smv[ROWS_PER_BLOCK];
    __shared__ int   smi[ROWS_PER_BLOCK];

    const int tid = threadIdx.x;
    const size_t blockRow = (size_t)blockIdx.x * ROWS_PER_BLOCK;

    // Stage z tile (128 rows x 64) coalesced into LDS.
    const float4* zg4 = (const float4*)(z + blockRow * D);
#pragma unroll
    for (int it = 0; it < 8; ++it) {
        int i = it * TPB + tid;            // 0..2047 float4s
        int row = i >> 4, col = i & 15;
        float4 v = zg4[i];
        *(float4*)&lds_z[row * LDS_STRIDE + col * 4] = v;
    }
    __syncthreads();

    const int rrow = tid & 127;   // row within tile (one row per thread)
    const int half = tid >> 7;    // which half of the codebook this thread scans

    // z row into registers (all constant indices -> stays in VGPRs).
    float zr[D];
#pragma unroll
    for (int c = 0; c < 16; ++c) {
        float4 v = *(const float4*)&lds_z[rrow * LDS_STRIDE + c * 4];
        zr[4*c+0] = v.x; zr[4*c+1] = v.y; zr[4*c+2] = v.z; zr[4*c+3] = v.w;
    }

    // zz = numpy-pairwise sum(z*z) — must match np bitwise (contraction off).
    float zz;
    {
#pragma clang fp contract(off)
        float r[8];
#pragma unroll
        for (int jj = 0; jj < 8; ++jj) { float t = zr[jj] * zr[jj]; r[jj] = t; }
#pragma unroll
        for (int i = 8; i < 64; i += 8) {
#pragma unroll
            for (int jj = 0; jj < 8; ++jj) { float t = zr[i+jj] * zr[i+jj]; r[jj] = r[jj] + t; }
        }
        zz = ((r[0]+r[1]) + (r[2]+r[3])) + ((r[4]+r[5]) + (r[6]+r[7]));
    }

    // Scan this thread's half of the codebook. j is wave-uniform
    // (readfirstlane) so the e-row and ee loads take the scalar path.
    float minv = __builtin_inff();
    int mini = 0;
    const int jbase = __builtin_amdgcn_readfirstlane(half << 9);  // 0 or 512
#pragma unroll 2
    for (int jj = 0; jj < 512; ++jj) {
        const int j = jbase + jj;
        const float4* ew4 = (const float4*)(emb + ((size_t)j << 6));
        float p0 = 0.f, p1 = 0.f, p2 = 0.f, p3 = 0.f;
#pragma unroll
        for (int c = 0; c < 16; ++c) {
            float4 e4 = ew4[c];
            p0 = fmaf(zr[4*c+0], e4.x, p0);
            p1 = fmaf(zr[4*c+1], e4.y, p1);
            p2 = fmaf(zr[4*c+2], e4.z, p2);
            p3 = fmaf(zr[4*c+3], e4.w, p3);
        }
        float dot = (p0 + p1) + (p2 + p3);
        float t1 = zz + ee[j];                 // mirrors np (zz + ee) rounding
        float d = fmaf(-2.0f, dot, t1);        // == round(t1 - 2*dot), exact mirror
        if (d < minv) { minv = d; mini = j; }  // strict < -> first index wins ties
    }

    // Merge the two code-halves per row (strict < keeps lower-index winner on tie).
    if (half) { smv[rrow] = minv; smi[rrow] = mini; }
    __syncthreads();
    if (!half) {
        float ov = smv[rrow];
        if (ov < minv) { minv = ov; mini = smi[rrow]; }

        // Gather winning code row; produce z_q = z + (q - z) (mirrors the
        // straight-through rounding) and the loss partial sum.
        const float4* qe4 = (const float4*)(emb + ((size_t)mini << 6));
        float s = 0.f;
#pragma unroll
        for (int c = 0; c < 16; ++c) {
            float4 q = qe4[c];
            float z0 = zr[4*c+0], z1 = zr[4*c+1], z2 = zr[4*c+2], z3 = zr[4*c+3];
            float d0 = q.x - z0, d1 = q.y - z1, d2 = q.z - z2, d3 = q.w - z3;
            s += d0*d0; s += d1*d1; s += d2*d2; s += d3*d3;
            float4 o;
            o.x = z0 + d0; o.y = z1 + d1; o.z = z2 + d2; o.w = z3 + d3;
            *(float4*)&lds_z[rrow * LDS_STRIDE + c * 4] = o;
        }
        out_idx[blockRow + rrow] = (float)mini;

        // loss = 1.25 * mean((q - z)^2): wave reduce + one atomic per wave.
#pragma unroll
        for (int off = 32; off; off >>= 1) s += __shfl_down(s, off);
        if ((tid & 63) == 0) atomicAdd(out_loss, s * loss_scale);
    }
    __syncthreads();

    // Coalesced z_q store. out_zq = d_out+1 is only 4B-aligned -> dword stores.
    const size_t obase = blockRow * D;
#pragma unroll
    for (int it = 0; it < 32; ++it) {
        int i = it * TPB + tid;            // 0..8191 floats
        int row = i >> 6, col = i & 63;
        out_zq[obase + i] = lds_z[row * LDS_STRIDE + col];
    }
}

extern "C" void kernel_launch(void* const* d_in, const int* in_sizes, int n_in,
                              void* d_out, int out_size, void* d_ws, size_t ws_size,
                              hipStream_t stream) {
    const float* z   = (const float*)d_in[0];
    const float* emb = (const float*)d_in[1];
    const int nz = in_sizes[0];          // 4194304
    const int N  = nz / D;               // 65536 rows
    const int ne = in_sizes[1] / D;      // 1024 codes

    float* out      = (float*)d_out;
    float* out_zq   = out + 1;
    float* out_idx  = out + 1 + (size_t)nz;
    float* ee       = (float*)d_ws;      // n_e floats of scratch

    const float loss_scale = 1.25f / (float)nz;  // exact: 1.25 * 2^-22

    hipMemsetAsync(out, 0, sizeof(float), stream);  // loss accumulator
    ee_kernel<<<(ne + TPB - 1) / TPB, TPB, 0, stream>>>(emb, ee, ne);
    vq_kernel<<<N / ROWS_PER_BLOCK, TPB, 0, stream>>>(z, emb, ee, out, out_zq,
                                                      out_idx, loss_scale);
}

// Round 2
// 262.943 us; speedup vs baseline: 1.4104x; 1.4104x over previous
//
#include <hip/hip_runtime.h>

// VQ-VAE quantizer: z [16,4096,64] f32, embedding [1024,64] f32.
// Outputs concatenated in d_out (float32): [0]=loss, [1..4194304]=z_q,
// [4194305..]=argmin indices (as float).
//
// Correctness-critical (verified absmax 0.0 in R1): argmin mirrors numpy
// bitwise. d = fmaf(-2,dot,(zz+ee)); zz/ee use numpy's pairwise 8-accumulator
// tree with fp-contract OFF; strict < gives first-index tie-break; segments
// merged in ascending order.
//
// R2 change: occupancy 23%->target 75%. 64 rows x 8 wave-uniform codebook
// segments per block (TPB=512) -> 8192 waves (32/CU requested, 24/CU after
// VGPR cap). ee folded into a block preamble (LDS), separate kernel removed.

#define D 64
#define NE 1024
#define SEGS 8
#define CPS 128              // codes per segment = NE/SEGS
#define ROWS 64              // rows per block
#define TPB 512
#define LDS_STRIDE 68        // 64 + 4 pad (keeps 16B alignment for float4)

__global__ __launch_bounds__(TPB, 6) void vq_kernel(const float* __restrict__ z,
                                                    const float* __restrict__ emb,
                                                    float* __restrict__ out_loss,
                                                    float* __restrict__ out_zq,
                                                    float* __restrict__ out_idx,
                                                    float loss_scale) {
    __shared__ float lds_z[ROWS * LDS_STRIDE];
    __shared__ float ee_lds[NE];
    __shared__ float smv[SEGS * ROWS];
    __shared__ int   smi[SEGS * ROWS];

    const int tid = threadIdx.x;
    const size_t blockRow = (size_t)blockIdx.x * ROWS;

    // --- Stage z tile (64 rows x 64) coalesced into LDS. ---
    const float4* zg4 = (const float4*)(z + blockRow * D);
#pragma unroll
    for (int it = 0; it < 2; ++it) {
        int i = it * TPB + tid;            // 0..1023 float4s
        int row = i >> 4, col = i & 15;
        float4 v = zg4[i];
        *(float4*)&lds_z[row * LDS_STRIDE + col * 4] = v;
    }

    // --- ee[j] = numpy-pairwise sum(e*e) for all 1024 codes (2 per thread).
    //     Must match np bitwise: 8 accumulators over stride-8 cols, contract off.
    {
#pragma clang fp contract(off)
#pragma unroll
        for (int cc = 0; cc < 2; ++cc) {
            const int j = tid + cc * TPB;
            const float4* e4 = (const float4*)(emb + ((size_t)j << 6));
            float4 a = e4[0], b = e4[1];
            float r[8];
            r[0] = a.x*a.x; r[1] = a.y*a.y; r[2] = a.z*a.z; r[3] = a.w*a.w;
            r[4] = b.x*b.x; r[5] = b.y*b.y; r[6] = b.z*b.z; r[7] = b.w*b.w;
#pragma unroll
            for (int g = 1; g < 8; ++g) {
                float4 c = e4[2*g], e = e4[2*g + 1];
                r[0] = r[0] + c.x*c.x; r[1] = r[1] + c.y*c.y;
                r[2] = r[2] + c.z*c.z; r[3] = r[3] + c.w*c.w;
                r[4] = r[4] + e.x*e.x; r[5] = r[5] + e.y*e.y;
                r[6] = r[6] + e.z*e.z; r[7] = r[7] + e.w*e.w;
            }
            ee_lds[j] = ((r[0]+r[1]) + (r[2]+r[3])) + ((r[4]+r[5]) + (r[6]+r[7]));
        }
    }
    __syncthreads();

    const int rrow = tid & (ROWS - 1);   // row within tile
    const int seg  = tid >> 6;           // wave-uniform codebook segment (0..7)

    // z row into registers.
    float zr[D];
#pragma unroll
    for (int c = 0; c < 16; ++c) {
        float4 v = *(const float4*)&lds_z[rrow * LDS_STRIDE + c * 4];
        zr[4*c+0] = v.x; zr[4*c+1] = v.y; zr[4*c+2] = v.z; zr[4*c+3] = v.w;
    }

    // zz = numpy-pairwise sum(z*z), contract off.
    float zz;
    {
#pragma clang fp contract(off)
        float r[8];
#pragma unroll
        for (int jj = 0; jj < 8; ++jj) { float t = zr[jj] * zr[jj]; r[jj] = t; }
#pragma unroll
        for (int i = 8; i < 64; i += 8) {
#pragma unroll
            for (int jj = 0; jj < 8; ++jj) { float t = zr[i+jj] * zr[i+jj]; r[jj] = r[jj] + t; }
        }
        zz = ((r[0]+r[1]) + (r[2]+r[3])) + ((r[4]+r[5]) + (r[6]+r[7]));
    }

    // --- Scan this wave's codebook segment. j wave-uniform -> scalar loads. ---
    float minv = __builtin_inff();
    int mini = 0;
    const int jbase = __builtin_amdgcn_readfirstlane(seg * CPS);
#pragma unroll 2
    for (int jj = 0; jj < CPS; ++jj) {
        const int j = jbase + jj;
        const float4* ew4 = (const float4*)(emb + ((size_t)j << 6));
        float p0 = 0.f, p1 = 0.f, p2 = 0.f, p3 = 0.f;
#pragma unroll
        for (int c = 0; c < 16; ++c) {
            float4 e4 = ew4[c];
            p0 = fmaf(zr[4*c+0], e4.x, p0);
            p1 = fmaf(zr[4*c+1], e4.y, p1);
            p2 = fmaf(zr[4*c+2], e4.z, p2);
            p3 = fmaf(zr[4*c+3], e4.w, p3);
        }
        float dot = (p0 + p1) + (p2 + p3);
        float t1 = zz + ee_lds[j];             // mirrors np (zz + ee) rounding
        float d = fmaf(-2.0f, dot, t1);        // == round(t1 - 2*dot)
        if (d < minv) { minv = d; mini = j; }  // strict < -> first index on tie
    }

    smv[seg * ROWS + rrow] = minv;
    smi[seg * ROWS + rrow] = mini;
    __syncthreads();

    if (tid < ROWS) {                          // wave 0 merges + epilogue
        float best = __builtin_inff();
        int bi = 0;
#pragma unroll
        for (int s = 0; s < SEGS; ++s) {       // ascending seg = ascending j
            float v = smv[s * ROWS + rrow];
            if (v < best) { best = v; bi = smi[s * ROWS + rrow]; }
        }

        // Gather winning code row; z_q = z + (q - z); loss partial.
        const float4* qe4 = (const float4*)(emb + ((size_t)bi << 6));
        float s = 0.f;
#pragma unroll
        for (int c = 0; c < 16; ++c) {
            float4 q = qe4[c];
            float z0 = zr[4*c+0], z1 = zr[4*c+1], z2 = zr[4*c+2], z3 = zr[4*c+3];
            float d0 = q.x - z0, d1 = q.y - z1, d2 = q.z - z2, d3 = q.w - z3;
            s += d0*d0; s += d1*d1; s += d2*d2; s += d3*d3;
            float4 o;
            o.x = z0 + d0; o.y = z1 + d1; o.z = z2 + d2; o.w = z3 + d3;
            *(float4*)&lds_z[rrow * LDS_STRIDE + c * 4] = o;
        }
        out_idx[blockRow + rrow] = (float)bi;

        // loss = 1.25 * mean((q-z)^2): wave reduce + one atomic per block.
#pragma unroll
        for (int off = 32; off; off >>= 1) s += __shfl_down(s, off);
        if (tid == 0) atomicAdd(out_loss, s * loss_scale);
    }
    __syncthreads();

    // Coalesced z_q store (out_zq = d_out+1 is 4B-aligned -> dword stores).
    const size_t obase = blockRow * D;
#pragma unroll
    for (int it = 0; it < 8; ++it) {
        int i = it * TPB + tid;            // 0..4095 floats
        int row = i >> 6, col = i & 63;
        out_zq[obase + i] = lds_z[row * LDS_STRIDE + col];
    }
}

extern "C" void kernel_launch(void* const* d_in, const int* in_sizes, int n_in,
                              void* d_out, int out_size, void* d_ws, size_t ws_size,
                              hipStream_t stream) {
    const float* z   = (const float*)d_in[0];
    const float* emb = (const float*)d_in[1];
    const int nz = in_sizes[0];          // 4194304
    const int N  = nz / D;               // 65536 rows

    float* out      = (float*)d_out;
    float* out_zq   = out + 1;
    float* out_idx  = out + 1 + (size_t)nz;

    const float loss_scale = 1.25f / (float)nz;

    hipMemsetAsync(out, 0, sizeof(float), stream);  // loss accumulator
    vq_kernel<<<N / ROWS, TPB, 0, stream>>>(z, emb, out, out_zq, out_idx, loss_scale);
}